// Round 1
// baseline (297.978 us; speedup 1.0000x reference)
//
#include <hip/hip_runtime.h>
#include <hip/hip_bf16.h>
#include <float.h>

#define H 2048
#define E 64
#define TOPK 8
#define TT 16   // tokens per block

typedef __attribute__((ext_vector_type(8))) short bf16x8;
typedef __attribute__((ext_vector_type(4))) float f32x4;
typedef __attribute__((ext_vector_type(4))) unsigned short us4;

__device__ __forceinline__ unsigned short f2bf(float f) {
  unsigned u = __float_as_uint(f);
  u += 0x7fffu + ((u >> 16) & 1u);   // RNE
  return (unsigned short)(u >> 16);
}
__device__ __forceinline__ float bf2f(unsigned short s) {
  return __uint_as_float(((unsigned)s) << 16);
}
__device__ __forceinline__ float wred_max(float v) {
#pragma unroll
  for (int o = 32; o > 0; o >>= 1) v = fmaxf(v, __shfl_xor(v, o));
  return v;
}
__device__ __forceinline__ float wred_sum(float v) {
#pragma unroll
  for (int o = 32; o > 0; o >>= 1) v += __shfl_xor(v, o);
  return v;
}

// Convert router_weight and expert_bias fp32 -> bf16 into workspace (L2-resident).
__global__ __launch_bounds__(256) void cvt_kernel(const float* __restrict__ W,
                                                  const float* __restrict__ eb,
                                                  unsigned short* __restrict__ Wb,
                                                  unsigned short* __restrict__ Bb) {
  int i = (blockIdx.x * 256 + threadIdx.x) * 4;
  const float* src;
  unsigned short* dst;
  int off;
  if (i < E * H) { src = W; dst = Wb; off = i; }
  else           { src = eb; dst = Bb; off = i - E * H; }
  float4 v = *(const float4*)(src + off);
  us4 r;
  r[0] = f2bf(v.x); r[1] = f2bf(v.y); r[2] = f2bf(v.z); r[3] = f2bf(v.w);
  *(us4*)(dst + off) = r;
}

template <bool USE_WS>
__global__ __launch_bounds__(256, 2) void moe_kernel(
    const float* __restrict__ x, const float* __restrict__ W,
    const float* __restrict__ rb, const float* __restrict__ eb,
    const unsigned short* __restrict__ Wb, const unsigned short* __restrict__ Bb,
    float* __restrict__ out) {
  // LDS: x tile (bf16, +8 pad -> 4-bank shift per row), logits, topk metadata
  __shared__ unsigned short xl[TT][H + 8];   // 65792 B
  __shared__ float lg[TT][E + 1];            // 4160 B
  __shared__ float msw[TT];
  __shared__ float mw[TT][TOPK];
  __shared__ int   mi[TT][TOPK];

  const int tid = threadIdx.x;
  const int t0  = blockIdx.x * TT;

  // ---- Phase A: stage x tile into LDS as bf16 (x read exactly once) ----
  {
    const int c0 = tid * 4;  // 0..1020
#pragma unroll 4
    for (int j = 0; j < TT; ++j) {
      const float* row = x + (size_t)(t0 + j) * H;
      float4 a = *(const float4*)(row + c0);
      float4 b = *(const float4*)(row + 1024 + c0);
      us4 ra, rbv;
      ra[0] = f2bf(a.x); ra[1] = f2bf(a.y); ra[2] = f2bf(a.z); ra[3] = f2bf(a.w);
      rbv[0] = f2bf(b.x); rbv[1] = f2bf(b.y); rbv[2] = f2bf(b.z); rbv[3] = f2bf(b.w);
      *(us4*)&xl[j][c0] = ra;
      *(us4*)&xl[j][1024 + c0] = rbv;
    }
  }
  __syncthreads();

  const int wv = tid >> 6, lane = tid & 63, quad = lane >> 4, m = lane & 15;

  // ---- Phase B: logits[16 tok x 64 exp] via MFMA; wave wv owns experts 16wv..16wv+15
  {
    const int e = wv * 16 + m;
    f32x4 acc = {0.f, 0.f, 0.f, 0.f};
    const unsigned short* xp = &xl[m][quad * 8];
    if (USE_WS) {
      const unsigned short* wp = Wb + (size_t)e * H + quad * 8;
#pragma unroll 8
      for (int it = 0; it < H / 32; ++it) {
        bf16x8 av = *(const bf16x8*)(xp + it * 32);
        bf16x8 bv = *(const bf16x8*)(wp + it * 32);
        acc = __builtin_amdgcn_mfma_f32_16x16x32_bf16(av, bv, acc, 0, 0, 0);
      }
    } else {
      const float* wp = W + (size_t)e * H + quad * 8;
#pragma unroll 4
      for (int it = 0; it < H / 32; ++it) {
        bf16x8 av = *(const bf16x8*)(xp + it * 32);
        float4 p = *(const float4*)(wp + it * 32);
        float4 q = *(const float4*)(wp + it * 32 + 4);
        bf16x8 bv;
        bv[0] = (short)f2bf(p.x); bv[1] = (short)f2bf(p.y);
        bv[2] = (short)f2bf(p.z); bv[3] = (short)f2bf(p.w);
        bv[4] = (short)f2bf(q.x); bv[5] = (short)f2bf(q.y);
        bv[6] = (short)f2bf(q.z); bv[7] = (short)f2bf(q.w);
        acc = __builtin_amdgcn_mfma_f32_16x16x32_bf16(av, bv, acc, 0, 0, 0);
      }
    }
    // C/D layout (verified): col = lane&15 (expert-in-tile), row = quad*4+reg (token)
#pragma unroll
    for (int r = 0; r < 4; ++r) lg[quad * 4 + r][wv * 16 + m] = acc[r];
  }
  __syncthreads();

  // ---- Phase B': softmax + top-8. Wave wv handles tokens 4wv..4wv+3; lane = expert.
  {
#pragma unroll
    for (int tt = 0; tt < 4; ++tt) {
      const int t = wv * 4 + tt;
      float l = lg[t][lane] + rb[lane];
      const float mx = wred_max(l);
      const float p = expf(l - mx);
      const float inv = 1.f / wred_sum(p);
      float sumw = 0.f;
      float lsel = l;
#pragma unroll
      for (int k = 0; k < TOPK; ++k) {
        const float mk = wred_max(lsel);
        const unsigned long long b = __ballot(lsel == mk);
        const int idx = __ffsll(b) - 1;          // tie -> lowest index (matches top_k)
        const float wk = expf(mk - mx) * inv;
        sumw += wk;
        if (lane == 0) { mw[t][k] = wk; mi[t][k] = idx; }
        if (lane == idx) lsel = -FLT_MAX;
      }
      if (lane == 0) msw[t] = sumw;
    }
  }
  __syncthreads();

  // ---- Phase C: out[t][h] = x[t][h]*sum_w + sum_k w_k * bias[idx_k][h] ----
  {
    const int c = tid * 8;  // 0..2040
    for (int t = 0; t < TT; ++t) {
      const float sw = msw[t];
      bf16x8 xv = *(const bf16x8*)&xl[t][c];
      float o[8];
#pragma unroll
      for (int i = 0; i < 8; ++i) o[i] = bf2f((unsigned short)xv[i]) * sw;
#pragma unroll
      for (int k = 0; k < TOPK; ++k) {
        const int e = mi[t][k];
        const float wk = mw[t][k];
        if (USE_WS) {
          bf16x8 bvv = *(const bf16x8*)(Bb + (size_t)e * H + c);
#pragma unroll
          for (int i = 0; i < 8; ++i) o[i] += wk * bf2f((unsigned short)bvv[i]);
        } else {
          float4 p = *(const float4*)(eb + (size_t)e * H + c);
          float4 q = *(const float4*)(eb + (size_t)e * H + c + 4);
          o[0] += wk * p.x; o[1] += wk * p.y; o[2] += wk * p.z; o[3] += wk * p.w;
          o[4] += wk * q.x; o[5] += wk * q.y; o[6] += wk * q.z; o[7] += wk * q.w;
        }
      }
      float* orow = out + (size_t)(t0 + t) * H + c;
      *(float4*)orow       = make_float4(o[0], o[1], o[2], o[3]);
      *(float4*)(orow + 4) = make_float4(o[4], o[5], o[6], o[7]);
    }
  }
}

extern "C" void kernel_launch(void* const* d_in, const int* in_sizes, int n_in,
                              void* d_out, int out_size, void* d_ws, size_t ws_size,
                              hipStream_t stream) {
  const float* x  = (const float*)d_in[0];
  const float* W  = (const float*)d_in[1];
  const float* rb = (const float*)d_in[2];
  const float* eb = (const float*)d_in[3];
  float* out = (float*)d_out;

  const int T = in_sizes[0] / H;     // 16384
  const int grid = T / TT;           // 1024

  const size_t need = (size_t)2 * E * H * sizeof(unsigned short);  // 512 KB
  if (ws_size >= need) {
    unsigned short* Wb = (unsigned short*)d_ws;
    unsigned short* Bb = Wb + E * H;
    cvt_kernel<<<(2 * E * H) / (256 * 4), 256, 0, stream>>>(W, eb, Wb, Bb);
    moe_kernel<true><<<grid, 256, 0, stream>>>(x, W, rb, eb, Wb, Bb, out);
  } else {
    moe_kernel<false><<<grid, 256, 0, stream>>>(x, W, rb, eb, nullptr, nullptr, out);
  }
}

// Round 2
// 285.291 us; speedup vs baseline: 1.0445x; 1.0445x over previous
//
#include <hip/hip_runtime.h>
#include <hip/hip_bf16.h>
#include <float.h>

#define H 2048
#define E 64
#define TOPK 8
#define TT 16    // tokens per block
#define NT 512   // threads per block (8 waves)

typedef __attribute__((ext_vector_type(8))) short bf16x8;
typedef __attribute__((ext_vector_type(4))) float f32x4;
typedef __attribute__((ext_vector_type(4))) unsigned short us4;

__device__ __forceinline__ unsigned short f2bf(float f) {
  unsigned u = __float_as_uint(f);
  u += 0x7fffu + ((u >> 16) & 1u);   // RNE
  return (unsigned short)(u >> 16);
}
__device__ __forceinline__ float bf2f(unsigned short s) {
  return __uint_as_float(((unsigned)s) << 16);
}
__device__ __forceinline__ float wred_max(float v) {
#pragma unroll
  for (int o = 32; o > 0; o >>= 1) v = fmaxf(v, __shfl_xor(v, o));
  return v;
}
__device__ __forceinline__ float wred_sum(float v) {
#pragma unroll
  for (int o = 32; o > 0; o >>= 1) v += __shfl_xor(v, o);
  return v;
}

// Convert router_weight and expert_bias fp32 -> bf16 into workspace (L2-resident).
__global__ __launch_bounds__(256) void cvt_kernel(const float* __restrict__ W,
                                                  const float* __restrict__ eb,
                                                  unsigned short* __restrict__ Wb,
                                                  unsigned short* __restrict__ Bb) {
  int i = (blockIdx.x * 256 + threadIdx.x) * 4;
  const float* src;
  unsigned short* dst;
  int off;
  if (i < E * H) { src = W; dst = Wb; off = i; }
  else           { src = eb; dst = Bb; off = i - E * H; }
  float4 v = *(const float4*)(src + off);
  us4 r;
  r[0] = f2bf(v.x); r[1] = f2bf(v.y); r[2] = f2bf(v.z); r[3] = f2bf(v.w);
  *(us4*)(dst + off) = r;
}

template <bool USE_WS>
__global__ __launch_bounds__(NT, 4) void moe_kernel(
    const float* __restrict__ x, const float* __restrict__ W,
    const float* __restrict__ rb, const float* __restrict__ eb,
    const unsigned short* __restrict__ Wb, const unsigned short* __restrict__ Bb,
    float* __restrict__ out) {
  // LDS: x tile (bf16, +8 pad -> 4-bank shift per row), logits, topk metadata
  __shared__ unsigned short xl[TT][H + 8];   // 65792 B
  __shared__ float lg[TT][E + 1];            // 4160 B
  __shared__ float msw[TT];
  __shared__ float mw[TT][TOPK];
  __shared__ int   mi[TT][TOPK];

  const int tid = threadIdx.x;
  const int t0  = blockIdx.x * TT;
  const int wv = tid >> 6, lane = tid & 63, quad = lane >> 4, m = lane & 15;

  // ---- Phase A: stage x tile into LDS as bf16; wave wv stages rows 2wv, 2wv+1 ----
  {
    const int r0 = wv * 2;
#pragma unroll
    for (int rr = 0; rr < 2; ++rr) {
      const float* row = x + (size_t)(t0 + r0 + rr) * H;
#pragma unroll
      for (int i = 0; i < 8; ++i) {
        const int c = (i * 64 + lane) * 4;
        float4 a = *(const float4*)(row + c);
        us4 ra;
        ra[0] = f2bf(a.x); ra[1] = f2bf(a.y); ra[2] = f2bf(a.z); ra[3] = f2bf(a.w);
        *(us4*)&xl[r0 + rr][c] = ra;
      }
    }
  }
  __syncthreads();

  // ---- Phase B: logits[16 tok x 64 exp] via MFMA; waves 0-3 own 16 experts each
  if (wv < 4) {
    const int e = wv * 16 + m;
    f32x4 acc = {0.f, 0.f, 0.f, 0.f};
    const unsigned short* xp = &xl[m][quad * 8];
    if (USE_WS) {
      const unsigned short* wp = Wb + (size_t)e * H + quad * 8;
#pragma unroll 8
      for (int it = 0; it < H / 32; ++it) {
        bf16x8 av = *(const bf16x8*)(xp + it * 32);
        bf16x8 bv = *(const bf16x8*)(wp + it * 32);
        acc = __builtin_amdgcn_mfma_f32_16x16x32_bf16(av, bv, acc, 0, 0, 0);
      }
    } else {
      const float* wp = W + (size_t)e * H + quad * 8;
#pragma unroll 4
      for (int it = 0; it < H / 32; ++it) {
        bf16x8 av = *(const bf16x8*)(xp + it * 32);
        float4 p = *(const float4*)(wp + it * 32);
        float4 q = *(const float4*)(wp + it * 32 + 4);
        bf16x8 bv;
        bv[0] = (short)f2bf(p.x); bv[1] = (short)f2bf(p.y);
        bv[2] = (short)f2bf(p.z); bv[3] = (short)f2bf(p.w);
        bv[4] = (short)f2bf(q.x); bv[5] = (short)f2bf(q.y);
        bv[6] = (short)f2bf(q.z); bv[7] = (short)f2bf(q.w);
        acc = __builtin_amdgcn_mfma_f32_16x16x32_bf16(av, bv, acc, 0, 0, 0);
      }
    }
    // C/D layout (verified): col = lane&15 (expert-in-tile), row = quad*4+reg (token)
#pragma unroll
    for (int r = 0; r < 4; ++r) lg[quad * 4 + r][wv * 16 + m] = acc[r];
  }
  __syncthreads();

  // ---- Phase B': softmax + top-8. Wave wv handles tokens 2wv, 2wv+1; lane = expert.
  {
#pragma unroll
    for (int tt = 0; tt < 2; ++tt) {
      const int t = wv * 2 + tt;
      float l = lg[t][lane] + rb[lane];
      const float mx = wred_max(l);
      const float p = expf(l - mx);
      const float inv = 1.f / wred_sum(p);
      float sumw = 0.f;
      float lsel = l;
#pragma unroll
      for (int k = 0; k < TOPK; ++k) {
        const float mk = wred_max(lsel);
        const unsigned long long b = __ballot(lsel == mk);
        const int idx = __ffsll(b) - 1;          // tie -> lowest index (matches top_k)
        const float wk = expf(mk - mx) * inv;
        sumw += wk;
        if (lane == 0) { mw[t][k] = wk; mi[t][k] = idx; }
        if (lane == idx) lsel = -FLT_MAX;
      }
      if (lane == 0) msw[t] = sumw;
    }
  }
  __syncthreads();

  // ---- Phase C: out[t][h] = x[t][h]*sum_w + sum_k w_k * bias[idx_k][h] ----
  {
    const int c = tid * 4;  // 0..2044, 512 threads cover a full row
    for (int t = 0; t < TT; ++t) {
      const float sw = msw[t];
      us4 xv = *(const us4*)&xl[t][c];
      float o[4];
#pragma unroll
      for (int i = 0; i < 4; ++i) o[i] = bf2f(xv[i]) * sw;
#pragma unroll
      for (int k = 0; k < TOPK; ++k) {
        const int e = mi[t][k];
        const float wk = mw[t][k];
        if (USE_WS) {
          us4 bv = *(const us4*)(Bb + (size_t)e * H + c);
#pragma unroll
          for (int i = 0; i < 4; ++i) o[i] += wk * bf2f(bv[i]);
        } else {
          float4 p = *(const float4*)(eb + (size_t)e * H + c);
          o[0] += wk * p.x; o[1] += wk * p.y; o[2] += wk * p.z; o[3] += wk * p.w;
        }
      }
      *(float4*)(out + (size_t)(t0 + t) * H + c) = make_float4(o[0], o[1], o[2], o[3]);
    }
  }
}

extern "C" void kernel_launch(void* const* d_in, const int* in_sizes, int n_in,
                              void* d_out, int out_size, void* d_ws, size_t ws_size,
                              hipStream_t stream) {
  const float* x  = (const float*)d_in[0];
  const float* W  = (const float*)d_in[1];
  const float* rb = (const float*)d_in[2];
  const float* eb = (const float*)d_in[3];
  float* out = (float*)d_out;

  const int T = in_sizes[0] / H;     // 16384
  const int grid = T / TT;           // 1024

  const size_t need = (size_t)2 * E * H * sizeof(unsigned short);  // 512 KB
  if (ws_size >= need) {
    unsigned short* Wb = (unsigned short*)d_ws;
    unsigned short* Bb = Wb + E * H;
    cvt_kernel<<<(2 * E * H) / (256 * 4), 256, 0, stream>>>(W, eb, Wb, Bb);
    moe_kernel<true><<<grid, NT, 0, stream>>>(x, W, rb, eb, Wb, Bb, out);
  } else {
    moe_kernel<false><<<grid, NT, 0, stream>>>(x, W, rb, eb, nullptr, nullptr, out);
  }
}